// Round 6
// baseline (166.308 us; speedup 1.0000x reference)
//
#include <hip/hip_runtime.h>

typedef unsigned short u16;
typedef unsigned int   u32;

typedef __attribute__((ext_vector_type(4)))  float  f32x4;
typedef __attribute__((ext_vector_type(16))) float  f32x16;
typedef __attribute__((ext_vector_type(4)))  u32    u32x4;
typedef __attribute__((ext_vector_type(8)))  __bf16 bf16x8;

#define B_  2
#define L_  2048
#define H_  16

// ---------- bf16 helpers ----------
__device__ static inline u16 f2bf(float f) {
  u32 u = __builtin_bit_cast(u32, f);
  u32 r = u + 0x7fffu + ((u >> 16) & 1u);
  return (u16)(r >> 16);
}
__device__ static inline u32 pack2(float a, float b) {   // RTNE pair pack
  return (u32)f2bf(a) | ((u32)f2bf(b) << 16);
}
// one-instruction truncating pair pack: dst = {hi16(b), hi16(a)} via v_perm_b32
__device__ static inline u32 pack2t(float a, float b) {
  return __builtin_amdgcn_perm(__builtin_bit_cast(u32, b),
                               __builtin_bit_cast(u32, a), 0x07060302u);
}

// permlane32_swap: a' = {a.lo32lanes, b.lo32lanes}, b' = {a.hi32lanes, b.hi32lanes}
__device__ static inline void swap32p(u32& a, u32& b) {
  auto r = __builtin_amdgcn_permlane32_swap(a, b, false, false);
  a = r[0]; b = r[1];
}

// async global->LDS, 16B/lane. LDS dest = wave-uniform base + lane*16.
__device__ static inline void gload_lds16(const u16* g, u16* lds) {
  __builtin_amdgcn_global_load_lds((__attribute__((address_space(1))) void*)(g),
                                   (__attribute__((address_space(3))) void*)(lds),
                                   16, 0, 0);
}

// ---------------------------------------------------------------------------
// fused fp32 -> bf16 pack for x, Wqkv, Wo (RTNE — GEMM inputs keep accuracy).
// softmax 1/sqrt(dk)=0.125 folded into W_q rows (power-of-2: bit-identical P).
// ---------------------------------------------------------------------------
__global__ __launch_bounds__(256) void cvt3_kernel(
    const float4* __restrict__ a, uint2* __restrict__ ao, int na,
    const float4* __restrict__ b, uint2* __restrict__ bo, int nb,
    const float4* __restrict__ c, uint2* __restrict__ co, int nc)
{
  const int step = gridDim.x * 256;
  constexpr int nq = 1024 * 1024 / 4;          // float4 count of the W_q rows
  for (int i = blockIdx.x * 256 + threadIdx.x; i < na; i += step) {
    float4 f = a[i];
    ao[i] = make_uint2(pack2(f.x, f.y), pack2(f.z, f.w));
  }
  for (int i = blockIdx.x * 256 + threadIdx.x; i < nb; i += step) {
    float4 f = b[i];
    const float s = (i < nq) ? 0.125f : 1.0f;
    bo[i] = make_uint2(pack2(f.x * s, f.y * s), pack2(f.z * s, f.w * s));
  }
  for (int i = blockIdx.x * 256 + threadIdx.x; i < nc; i += step) {
    float4 f = c[i];
    co[i] = make_uint2(pack2(f.x, f.y), pack2(f.z, f.w));
  }
}

// ---------------------------------------------------------------------------
// GEMM: C[M,N] = A[M,K] @ Bt[N,K]^T, bf16 in, fp32 MFMA accumulate.
// m97 structure + source-permuted XOR chunk swizzle (R6).
// R15: GEMM1 uses NT=96 -> grid 32x32 = 1024 blocks = 4 blocks/CU, the
// co-residency regime where m102 measured the structure's best rate
// (1/CU: 320 TF, 3/CU: ~650 (R6-R14 measured), 4/CU: 833 TF @ N=4096).
// LDS (128+96)*64*2B = 28 KiB -> 4 resident. GEMM2 keeps NT=64 + DBUF.
// ---------------------------------------------------------------------------
template <bool OUT_F32, int NT, bool DBUF>
__global__ __launch_bounds__(256) void gemm_bt_kernel(
    const u16* __restrict__ A, const u16* __restrict__ Bt, void* __restrict__ Cv,
    const int K, const int N)
{
  constexpr int NB = DBUF ? 2 : 1;
  constexpr int JT = NT / 32;                    // j-tiles per wave
  __shared__ __attribute__((aligned(16))) u16 Al[NB][128 * 64];
  __shared__ __attribute__((aligned(16))) u16 Bl[NB][NT * 64];

  const int tid  = threadIdx.x;
  const int w    = tid >> 6;
  const int lane = tid & 63;
  const int m0 = blockIdx.y * 128;
  const int n0 = blockIdx.x * NT;
  const int mo = (w >> 1) * 64;
  const int no = (w & 1) * (NT / 2);

  const int sr8  = lane >> 3;                    // staging row-in-group
  const int scol = (((lane & 7) ^ ((lane >> 3) & 7)) * 8);   // swizzled source chunk

  const f32x4 zero = {0.f, 0.f, 0.f, 0.f};
  f32x4 acc[4][JT];
  #pragma unroll
  for (int i = 0; i < 4; ++i)
    #pragma unroll
    for (int j = 0; j < JT; ++j) acc[i][j] = zero;

  const int frow = lane & 15;
  const int fg   = lane >> 4;

  auto stage = [&](int buf, int k0) {
    #pragma unroll
    for (int inst = 0; inst < 4; ++inst) {
      const int r = w * 32 + inst * 8 + sr8;
      gload_lds16(A + (size_t)(m0 + r) * K + k0 + scol, &Al[buf][(w * 32 + inst * 8) * 64]);
    }
    #pragma unroll
    for (int inst = 0; inst < NT / 32; ++inst) {
      const int r = w * (NT / 4) + inst * 8 + sr8;
      gload_lds16(Bt + (size_t)(n0 + r) * K + k0 + scol, &Bl[buf][(w * (NT / 4) + inst * 8) * 64]);
    }
  };

  if (DBUF) stage(0, 0);

  int cur = 0;
  for (int k0 = 0; k0 < K; k0 += 64) {
    __syncthreads();
    if (DBUF) {
      if (k0 + 64 < K) stage(cur ^ 1, k0 + 64);
    } else {
      stage(0, k0);
      __syncthreads();
    }
    #pragma unroll
    for (int ks = 0; ks < 2; ++ks) {
      const int fco = ((ks * 4 + fg) ^ (frow & 7)) * 8;      // swizzled read chunk
      bf16x8 af[4], bfr[JT];
      #pragma unroll
      for (int i = 0; i < 4; ++i)
        af[i] = *(const bf16x8*)&Al[cur][(mo + i * 16 + frow) * 64 + fco];
      #pragma unroll
      for (int j = 0; j < JT; ++j)
        bfr[j] = *(const bf16x8*)&Bl[cur][(no + j * 16 + frow) * 64 + fco];
      #pragma unroll
      for (int i = 0; i < 4; ++i)
        #pragma unroll
        for (int j = 0; j < JT; ++j)
          acc[i][j] = __builtin_amdgcn_mfma_f32_16x16x32_bf16(af[i], bfr[j], acc[i][j], 0, 0, 0);
    }
    if (DBUF) cur ^= 1;
  }

  const int crow0 = m0 + mo + (lane >> 4) * 4;
  const int ccol0 = n0 + no + (lane & 15);
  #pragma unroll
  for (int i = 0; i < 4; ++i)
    #pragma unroll
    for (int j = 0; j < JT; ++j)
      #pragma unroll
      for (int r = 0; r < 4; ++r) {
        const size_t idx = (size_t)(crow0 + i * 16 + r) * N + (ccol0 + j * 16);
        if (OUT_F32) ((float*)Cv)[idx] = acc[i][j][r];
        else         ((u16*)Cv)[idx]   = f2bf(acc[i][j][r]);
      }
}

// ---------------------------------------------------------------------------
// MFMA causal flash attention — R12 structure (unchanged this round).
// 32x32 MFMA, 256 thr, 4 waves (qh x kh), 4 blocks/CU, P in-register via
// permlane32_swap, k-half combine via LDS overlay.
// ---------------------------------------------------------------------------
__global__ __launch_bounds__(256, 4) void attn_mfma_kernel(const u16* __restrict__ qkv,
                                                           u16* __restrict__ y)
{
  __shared__ __attribute__((aligned(16))) unsigned char smem[32768];

  const int tid  = threadIdx.x;
  const int w    = tid >> 6;                   // wave 0..3
  const int lane = tid & 63;
  const int ql   = lane & 31;                  // q-col (also d-row / k-row index)
  const int hi   = lane >> 5;
  const int qh   = w >> 1;                     // q-half of the 64-q tile
  const int kh   = w & 1;                      // k-half split
  const int bh   = blockIdx.x;                 // bh on x => XCD affinity
  const int bb   = bh >> 4;
  const int hh   = bh & 15;
  const size_t rb = (size_t)bb * L_;

  // load-balance remap: blocks at id, id+256, id+512, id+768 (same CU under
  // round-robin dispatch) get qt = {a, 31-a, 8+a, 23-a} -> 66 tiles total.
  const int a  = blockIdx.y & 7;
  const int cc = blockIdx.y >> 3;
  const int qt = (cc == 0) ? a : (cc == 1) ? (31 - a) : (cc == 2) ? (8 + a) : (23 - a);

  u16* Kt   = (u16*)(smem);                    // [buf*4096 + row*64 + col] bf16
  u32* Vtd  = (u32*)(smem + 16384);            // [buf*2048 + d*32 + kp] u32
  float* Ocmb = (float*)smem;                  // combine overlay [16][256] f32
  float* Lcmb = (float*)(smem + 16384);        // combine overlay [64] f32

  // V staging: thread handles key-pair column kkp, d-rows dc*8 .. dc*8+7
  const int kkp = lane & 31;
  const int dc  = 2 * w + (lane >> 5);         // 0..7

  // K staging (R6 swizzle): wave w stages rows w*16 .. w*16+15
  const int ksr = w * 16 + (lane >> 3);
  const int ksc = (((lane & 7) ^ ((lane >> 3) & 7)) * 8);

  const int q0 = qt * 64;
  const int qb = q0 + qh * 32;                 // wave's q-base; lane's q = qb+ql
  const int n  = qt + 1;                       // k-tiles for this tile

  // Q B-frags (32x32x16): qf[s] = Q[qb+ql][d = 16s + 8hi .. +7], W_q pre-scaled
  bf16x8 qf[4];
  #pragma unroll
  for (int s = 0; s < 4; ++s)
    qf[s] = *(const bf16x8*)(qkv + (rb + qb + ql) * 3072 + hh * 64 + s * 16 + 8 * hi);

  f32x16 oacc0 = {}, oacc1 = {};               // O^T d-tiles 0/1 (64 d x 32 q)
  float lsum = 0.f;

  auto stageK = [&](int buf, int kt) {
    #pragma unroll
    for (int inst = 0; inst < 2; ++inst)
      gload_lds16(qkv + (rb + kt + ksr + inst * 8) * 3072 + 1024 + hh * 64 + ksc,
                  &Kt[buf * 4096 + (w * 16 + inst * 8) * 64]);
  };
  auto loadV = [&](int kt, uint4& va, uint4& vb) {
    const u16* vp = qkv + (rb + kt + 2 * kkp) * 3072 + 2048 + hh * 64 + dc * 8;
    va = *(const uint4*)vp;
    vb = *(const uint4*)(vp + 3072);
  };
  auto writeV = [&](int buf, uint4 va, uint4 vb) {
    u16 a16[8], b16[8];
    *(uint4*)a16 = va; *(uint4*)b16 = vb;
    #pragma unroll
    for (int i = 0; i < 8; ++i)
      Vtd[buf * 2048 + (dc * 8 + i) * 32 + 4 * ((kkp >> 2) ^ i) + (kkp & 3)] =
          (u32)a16[i] | ((u32)b16[i] << 16);
  };

  // ---- prologue: stage tile 0 into buffer 0 ----
  {
    stageK(0, 0);
    uint4 va, vb;
    loadV(0, va, vb);
    writeV(0, va, vb);
  }

  int cur = 0;
  for (int it = 0; it < n; ++it) {
    __syncthreads();   // publishes K/V[cur]

    const int  kt       = it * 64;
    const bool havenext = (it + 1) < n;
    uint4 va, vb;
    if (havenext) {
      stageK(cur ^ 1, kt + 64);
      loadV(kt + 64, va, vb);
    }

    const bool diag = (kt == q0);
    if (!(diag && kh > qh)) {                  // (qh=0,kh=1) diag tile: all masked
      // S^T = K Q^T over this wave's k-half: 32q x 32k, chained over d (4x16)
      f32x16 sacc = {};
      __builtin_amdgcn_s_setprio(1);
      #pragma unroll
      for (int s = 0; s < 4; ++s) {
        bf16x8 kf = *(const bf16x8*)&Kt[cur * 4096 + (kh * 32 + ql) * 64 +
                                        (((2 * s + hi) ^ (ql & 7)) * 8)];
        sacc = __builtin_amdgcn_mfma_f32_32x32x16_bf16(kf, qf[s], sacc, 0, 0, 0);
      }
      __builtin_amdgcn_s_setprio(0);

      // p = exp(s); triangular mask only when kh==qh on the diag tile.
      // k-row(reg r) = (r&3) + 8*(r>>2) + 4*hi; pack pairs (rows 2j,2j+1).
      u32 u[8];
      if (diag && kh == qh) {
        #pragma unroll
        for (int j = 0; j < 8; ++j) {
          const int r0  = 2 * j;
          const int k0r = (r0 & 3) + 8 * (r0 >> 2) + 4 * hi;
          const float p0 = (k0r     > ql) ? 0.f : __expf(sacc[r0]);
          const float p1 = (k0r + 1 > ql) ? 0.f : __expf(sacc[r0 + 1]);
          lsum += p0 + p1;
          u[j] = pack2t(p0, p1);
        }
      } else {
        #pragma unroll
        for (int j = 0; j < 8; ++j) {
          const float p0 = __expf(sacc[2 * j]);
          const float p1 = __expf(sacc[2 * j + 1]);
          lsum += p0 + p1;
          u[j] = pack2t(p0, p1);
        }
      }

      // P^T B-frags in-register: swap k-row pair-groups across lane halves.
      swap32p(u[0], u[2]); swap32p(u[1], u[3]);      // ks=0: k-rows 8hi+0..7
      swap32p(u[4], u[6]); swap32p(u[5], u[7]);      // ks=1
      const bf16x8 pf0 = __builtin_bit_cast(bf16x8, (u32x4){u[0], u[1], u[2], u[3]});
      const bf16x8 pf1 = __builtin_bit_cast(bf16x8, (u32x4){u[4], u[5], u[6], u[7]});

      // O^T += V^T P^T (A = V^T[d 32-rows x 16 k], per d-tile, per 16-k step)
      __builtin_amdgcn_s_setprio(1);
      #pragma unroll
      for (int dt = 0; dt < 2; ++dt) {
        f32x16& oa = dt ? oacc1 : oacc0;
        const int d = dt * 32 + ql;
        bf16x8 vf0 = *(const bf16x8*)&Vtd[cur * 2048 + d * 32 + 4 * ((4 * kh + hi) ^ (ql & 7))];
        oa = __builtin_amdgcn_mfma_f32_32x32x16_bf16(vf0, pf0, oa, 0, 0, 0);
        bf16x8 vf1 = *(const bf16x8*)&Vtd[cur * 2048 + d * 32 + 4 * ((4 * kh + 2 + hi) ^ (ql & 7))];
        oa = __builtin_amdgcn_mfma_f32_32x32x16_bf16(vf1, pf1, oa, 0, 0, 0);
      }
      __builtin_amdgcn_s_setprio(0);
    }

    if (havenext) writeV(cur ^ 1, va, vb);
    cur ^= 1;
  }

  // l: combine the two hi-halves (each covers half the wave's k-rows)
  lsum += __shfl_xor(lsum, 32);

  // ---- combine the two k-half waves' partials (O = O0 + O1, l = l0 + l1) ----
  __syncthreads();   // all K/V LDS use done before overlaying combine area
  if (kh == 1) {
    #pragma unroll
    for (int dt = 0; dt < 2; ++dt)
      #pragma unroll
      for (int rq = 0; rq < 4; ++rq) {
        const f32x16& oa = dt ? oacc1 : oacc0;
        *(f32x4*)&Ocmb[(qh * 8 + dt * 4 + rq) * 256 + lane * 4] =
            (f32x4){oa[4 * rq], oa[4 * rq + 1], oa[4 * rq + 2], oa[4 * rq + 3]};
      }
    if (hi == 0) Lcmb[qh * 32 + ql] = lsum;
  }
  __syncthreads();
  if (kh == 0) {
    const float inv = 1.f / (lsum + Lcmb[qh * 32 + ql]);
    u16* yp = y + (rb + qb + ql) * 1024 + hh * 64;
    #pragma unroll
    for (int dt = 0; dt < 2; ++dt)
      #pragma unroll
      for (int rq = 0; rq < 4; ++rq) {
        const f32x16& oa = dt ? oacc1 : oacc0;
        const f32x4 oc = *(const f32x4*)&Ocmb[(qh * 8 + dt * 4 + rq) * 256 + lane * 4];
        const float v0 = (oa[4 * rq]     + oc[0]) * inv;
        const float v1 = (oa[4 * rq + 1] + oc[1]) * inv;
        const float v2 = (oa[4 * rq + 2] + oc[2]) * inv;
        const float v3 = (oa[4 * rq + 3] + oc[3]) * inv;
        // d = dt*32 + 8*rq + 4*hi + {0..3}
        *(uint2*)(yp + dt * 32 + 8 * rq + 4 * hi) = make_uint2(pack2(v0, v1), pack2(v2, v3));
      }
  }
}

// ---------------------------------------------------------------------------
extern "C" void kernel_launch(void* const* d_in, const int* in_sizes, int n_in,
                              void* d_out, int out_size, void* d_ws, size_t ws_size,
                              hipStream_t stream)
{
  const float* x    = (const float*)d_in[0];   // [B*L, 1024] fp32
  const float* Wqkv = (const float*)d_in[1];   // [3072, 1024] fp32
  const float* Wo   = (const float*)d_in[2];   // [1024, 1024] fp32
  float* out = (float*)d_out;                  // [B*L, 1024] fp32

  u16* xb    = (u16*)d_ws;                      // [4096,1024]  8 MiB
  u16* Wqkvb = xb    + (size_t)4096 * 1024;     // [3072,1024]  6 MiB
  u16* Wob   = Wqkvb + (size_t)3072 * 1024;     // [1024,1024]  2 MiB
  u16* qkv   = Wob   + (size_t)1024 * 1024;     // [4096,3072] 24 MiB
  u16* y     = qkv   + (size_t)4096 * 3072;     // [4096,1024]  8 MiB

  cvt3_kernel<<<dim3(2048), dim3(256), 0, stream>>>(
      (const float4*)x,    (uint2*)xb,    4096 * 1024 / 4,
      (const float4*)Wqkv, (uint2*)Wqkvb, 3072 * 1024 / 4,
      (const float4*)Wo,   (uint2*)Wob,   1024 * 1024 / 4);

  // qkv = x @ Wqkv^T   (M=4096, N=3072, K=1024)
  // R15: NT=96 -> grid 32x32 = 1024 blocks = 4/CU (m102's best-residency regime)
  gemm_bt_kernel<false, 96, false><<<dim3(3072 / 96, 4096 / 128), dim3(256), 0, stream>>>(
      xb, Wqkvb, qkv, 1024, 3072);
  // causal MHA -> y [4096, 1024] bf16  (R12: 32x32 MFMA, 256 thr, 4 blk/CU)
  attn_mfma_kernel<<<dim3(B_ * H_, 32), dim3(256), 0, stream>>>(qkv, y);
  // out = y @ Wo^T     (M=4096, N=1024, K=1024), fp32 out
  gemm_bt_kernel<true, 64, true><<<dim3(1024 / 64, 4096 / 128), dim3(256), 0, stream>>>(
      y, Wob, out, 1024, 1024);
}

// Round 7
// 164.325 us; speedup vs baseline: 1.0121x; 1.0121x over previous
//
#include <hip/hip_runtime.h>

typedef unsigned short u16;
typedef unsigned int   u32;

typedef __attribute__((ext_vector_type(4)))  float  f32x4;
typedef __attribute__((ext_vector_type(16))) float  f32x16;
typedef __attribute__((ext_vector_type(4)))  u32    u32x4;
typedef __attribute__((ext_vector_type(8)))  __bf16 bf16x8;

#define B_  2
#define L_  2048
#define H_  16

// ---------- bf16 helpers ----------
__device__ static inline u16 f2bf(float f) {
  u32 u = __builtin_bit_cast(u32, f);
  u32 r = u + 0x7fffu + ((u >> 16) & 1u);
  return (u16)(r >> 16);
}
__device__ static inline u32 pack2(float a, float b) {   // RTNE pair pack
  return (u32)f2bf(a) | ((u32)f2bf(b) << 16);
}
// one-instruction truncating pair pack: dst = {hi16(b), hi16(a)} via v_perm_b32
__device__ static inline u32 pack2t(float a, float b) {
  return __builtin_amdgcn_perm(__builtin_bit_cast(u32, b),
                               __builtin_bit_cast(u32, a), 0x07060302u);
}

// permlane32_swap: a' = {a.lo32lanes, b.lo32lanes}, b' = {a.hi32lanes, b.hi32lanes}
__device__ static inline void swap32p(u32& a, u32& b) {
  auto r = __builtin_amdgcn_permlane32_swap(a, b, false, false);
  a = r[0]; b = r[1];
}

// async global->LDS, 16B/lane. LDS dest = wave-uniform base + lane*16.
__device__ static inline void gload_lds16(const u16* g, u16* lds) {
  __builtin_amdgcn_global_load_lds((__attribute__((address_space(1))) void*)(g),
                                   (__attribute__((address_space(3))) void*)(lds),
                                   16, 0, 0);
}

// ---------------------------------------------------------------------------
// fused fp32 -> bf16 pack for x, Wqkv, Wo (RTNE — GEMM inputs keep accuracy).
// softmax 1/sqrt(dk)=0.125 folded into W_q rows (power-of-2: bit-identical P).
// ---------------------------------------------------------------------------
__global__ __launch_bounds__(256) void cvt3_kernel(
    const float4* __restrict__ a, uint2* __restrict__ ao, int na,
    const float4* __restrict__ b, uint2* __restrict__ bo, int nb,
    const float4* __restrict__ c, uint2* __restrict__ co, int nc)
{
  const int step = gridDim.x * 256;
  constexpr int nq = 1024 * 1024 / 4;          // float4 count of the W_q rows
  for (int i = blockIdx.x * 256 + threadIdx.x; i < na; i += step) {
    float4 f = a[i];
    ao[i] = make_uint2(pack2(f.x, f.y), pack2(f.z, f.w));
  }
  for (int i = blockIdx.x * 256 + threadIdx.x; i < nb; i += step) {
    float4 f = b[i];
    const float s = (i < nq) ? 0.125f : 1.0f;
    bo[i] = make_uint2(pack2(f.x * s, f.y * s), pack2(f.z * s, f.w * s));
  }
  for (int i = blockIdx.x * 256 + threadIdx.x; i < nc; i += step) {
    float4 f = c[i];
    co[i] = make_uint2(pack2(f.x, f.y), pack2(f.z, f.w));
  }
}

// ---------------------------------------------------------------------------
// GEMM: C[M,N] = A[M,K] @ Bt[N,K]^T, bf16 in, fp32 MFMA accumulate.
// m97 structure + source-permuted XOR chunk swizzle (R6).
// R16: GEMM1 back to the measured-best config NT=128 (R12: 645 TF). Five
// rounds of alternatives (8-phase x2, NT=96 4/CU) all lost to it:
// tile-efficiency (128^2 = best per m92/m103) + VGPR=164 caps residency at
// 3/CU regardless, so 128^2 @ grid 768 = 3/CU is this structure's optimum
// at M=4096,N=3072,K=1024. GEMM2 keeps NT=64 + DBUF.
// ---------------------------------------------------------------------------
template <bool OUT_F32, int NT, bool DBUF>
__global__ __launch_bounds__(256) void gemm_bt_kernel(
    const u16* __restrict__ A, const u16* __restrict__ Bt, void* __restrict__ Cv,
    const int K, const int N)
{
  constexpr int NB = DBUF ? 2 : 1;
  constexpr int JT = NT / 32;                    // j-tiles per wave
  __shared__ __attribute__((aligned(16))) u16 Al[NB][128 * 64];
  __shared__ __attribute__((aligned(16))) u16 Bl[NB][NT * 64];

  const int tid  = threadIdx.x;
  const int w    = tid >> 6;
  const int lane = tid & 63;
  const int m0 = blockIdx.y * 128;
  const int n0 = blockIdx.x * NT;
  const int mo = (w >> 1) * 64;
  const int no = (w & 1) * (NT / 2);

  const int sr8  = lane >> 3;                    // staging row-in-group
  const int scol = (((lane & 7) ^ ((lane >> 3) & 7)) * 8);   // swizzled source chunk

  const f32x4 zero = {0.f, 0.f, 0.f, 0.f};
  f32x4 acc[4][JT];
  #pragma unroll
  for (int i = 0; i < 4; ++i)
    #pragma unroll
    for (int j = 0; j < JT; ++j) acc[i][j] = zero;

  const int frow = lane & 15;
  const int fg   = lane >> 4;

  auto stage = [&](int buf, int k0) {
    #pragma unroll
    for (int inst = 0; inst < 4; ++inst) {
      const int r = w * 32 + inst * 8 + sr8;
      gload_lds16(A + (size_t)(m0 + r) * K + k0 + scol, &Al[buf][(w * 32 + inst * 8) * 64]);
    }
    #pragma unroll
    for (int inst = 0; inst < NT / 32; ++inst) {
      const int r = w * (NT / 4) + inst * 8 + sr8;
      gload_lds16(Bt + (size_t)(n0 + r) * K + k0 + scol, &Bl[buf][(w * (NT / 4) + inst * 8) * 64]);
    }
  };

  if (DBUF) stage(0, 0);

  int cur = 0;
  for (int k0 = 0; k0 < K; k0 += 64) {
    __syncthreads();
    if (DBUF) {
      if (k0 + 64 < K) stage(cur ^ 1, k0 + 64);
    } else {
      stage(0, k0);
      __syncthreads();
    }
    #pragma unroll
    for (int ks = 0; ks < 2; ++ks) {
      const int fco = ((ks * 4 + fg) ^ (frow & 7)) * 8;      // swizzled read chunk
      bf16x8 af[4], bfr[JT];
      #pragma unroll
      for (int i = 0; i < 4; ++i)
        af[i] = *(const bf16x8*)&Al[cur][(mo + i * 16 + frow) * 64 + fco];
      #pragma unroll
      for (int j = 0; j < JT; ++j)
        bfr[j] = *(const bf16x8*)&Bl[cur][(no + j * 16 + frow) * 64 + fco];
      #pragma unroll
      for (int i = 0; i < 4; ++i)
        #pragma unroll
        for (int j = 0; j < JT; ++j)
          acc[i][j] = __builtin_amdgcn_mfma_f32_16x16x32_bf16(af[i], bfr[j], acc[i][j], 0, 0, 0);
    }
    if (DBUF) cur ^= 1;
  }

  const int crow0 = m0 + mo + (lane >> 4) * 4;
  const int ccol0 = n0 + no + (lane & 15);
  #pragma unroll
  for (int i = 0; i < 4; ++i)
    #pragma unroll
    for (int j = 0; j < JT; ++j)
      #pragma unroll
      for (int r = 0; r < 4; ++r) {
        const size_t idx = (size_t)(crow0 + i * 16 + r) * N + (ccol0 + j * 16);
        if (OUT_F32) ((float*)Cv)[idx] = acc[i][j][r];
        else         ((u16*)Cv)[idx]   = f2bf(acc[i][j][r]);
      }
}

// ---------------------------------------------------------------------------
// MFMA causal flash attention — R12 structure; R16: longest-first dispatch.
// 32x32 MFMA, 256 thr, 4 waves (qh x kh), 4 blocks/CU, P in-register via
// permlane32_swap, k-half combine via LDS overlay.
// qt remap: CU-group {y=a, a+8, a+16, a+24} gets qt {31-a, a, 23-a, 8+a}
// (same 66-tile per-CU sum as before, but the LONGEST blocks are in the
// first dispatched y-batch -> drain tail compressed).
// ---------------------------------------------------------------------------
__global__ __launch_bounds__(256, 4) void attn_mfma_kernel(const u16* __restrict__ qkv,
                                                           u16* __restrict__ y)
{
  __shared__ __attribute__((aligned(16))) unsigned char smem[32768];

  const int tid  = threadIdx.x;
  const int w    = tid >> 6;                   // wave 0..3
  const int lane = tid & 63;
  const int ql   = lane & 31;                  // q-col (also d-row / k-row index)
  const int hi   = lane >> 5;
  const int qh   = w >> 1;                     // q-half of the 64-q tile
  const int kh   = w & 1;                      // k-half split
  const int bh   = blockIdx.x;                 // bh on x => XCD affinity
  const int bb   = bh >> 4;
  const int hh   = bh & 15;
  const size_t rb = (size_t)bb * L_;

  // load-balance remap, longest-first (R16): see header comment.
  const int a  = blockIdx.y & 7;
  const int cc = blockIdx.y >> 3;
  const int qt = (cc == 0) ? (31 - a) : (cc == 1) ? a : (cc == 2) ? (23 - a) : (8 + a);

  u16* Kt   = (u16*)(smem);                    // [buf*4096 + row*64 + col] bf16
  u32* Vtd  = (u32*)(smem + 16384);            // [buf*2048 + d*32 + kp] u32
  float* Ocmb = (float*)smem;                  // combine overlay [16][256] f32
  float* Lcmb = (float*)(smem + 16384);        // combine overlay [64] f32

  // V staging: thread handles key-pair column kkp, d-rows dc*8 .. dc*8+7
  const int kkp = lane & 31;
  const int dc  = 2 * w + (lane >> 5);         // 0..7

  // K staging (R6 swizzle): wave w stages rows w*16 .. w*16+15
  const int ksr = w * 16 + (lane >> 3);
  const int ksc = (((lane & 7) ^ ((lane >> 3) & 7)) * 8);

  const int q0 = qt * 64;
  const int qb = q0 + qh * 32;                 // wave's q-base; lane's q = qb+ql
  const int n  = qt + 1;                       // k-tiles for this tile

  // Q B-frags (32x32x16): qf[s] = Q[qb+ql][d = 16s + 8hi .. +7], W_q pre-scaled
  bf16x8 qf[4];
  #pragma unroll
  for (int s = 0; s < 4; ++s)
    qf[s] = *(const bf16x8*)(qkv + (rb + qb + ql) * 3072 + hh * 64 + s * 16 + 8 * hi);

  f32x16 oacc0 = {}, oacc1 = {};               // O^T d-tiles 0/1 (64 d x 32 q)
  float lsum = 0.f;

  auto stageK = [&](int buf, int kt) {
    #pragma unroll
    for (int inst = 0; inst < 2; ++inst)
      gload_lds16(qkv + (rb + kt + ksr + inst * 8) * 3072 + 1024 + hh * 64 + ksc,
                  &Kt[buf * 4096 + (w * 16 + inst * 8) * 64]);
  };
  auto loadV = [&](int kt, uint4& va, uint4& vb) {
    const u16* vp = qkv + (rb + kt + 2 * kkp) * 3072 + 2048 + hh * 64 + dc * 8;
    va = *(const uint4*)vp;
    vb = *(const uint4*)(vp + 3072);
  };
  auto writeV = [&](int buf, uint4 va, uint4 vb) {
    u16 a16[8], b16[8];
    *(uint4*)a16 = va; *(uint4*)b16 = vb;
    #pragma unroll
    for (int i = 0; i < 8; ++i)
      Vtd[buf * 2048 + (dc * 8 + i) * 32 + 4 * ((kkp >> 2) ^ i) + (kkp & 3)] =
          (u32)a16[i] | ((u32)b16[i] << 16);
  };

  // ---- prologue: stage tile 0 into buffer 0 ----
  {
    stageK(0, 0);
    uint4 va, vb;
    loadV(0, va, vb);
    writeV(0, va, vb);
  }

  int cur = 0;
  for (int it = 0; it < n; ++it) {
    __syncthreads();   // publishes K/V[cur]

    const int  kt       = it * 64;
    const bool havenext = (it + 1) < n;
    uint4 va, vb;
    if (havenext) {
      stageK(cur ^ 1, kt + 64);
      loadV(kt + 64, va, vb);
    }

    const bool diag = (kt == q0);
    if (!(diag && kh > qh)) {                  // (qh=0,kh=1) diag tile: all masked
      // S^T = K Q^T over this wave's k-half: 32q x 32k, chained over d (4x16)
      f32x16 sacc = {};
      __builtin_amdgcn_s_setprio(1);
      #pragma unroll
      for (int s = 0; s < 4; ++s) {
        bf16x8 kf = *(const bf16x8*)&Kt[cur * 4096 + (kh * 32 + ql) * 64 +
                                        (((2 * s + hi) ^ (ql & 7)) * 8)];
        sacc = __builtin_amdgcn_mfma_f32_32x32x16_bf16(kf, qf[s], sacc, 0, 0, 0);
      }
      __builtin_amdgcn_s_setprio(0);

      // p = exp(s); triangular mask only when kh==qh on the diag tile.
      // k-row(reg r) = (r&3) + 8*(r>>2) + 4*hi; pack pairs (rows 2j,2j+1).
      u32 u[8];
      if (diag && kh == qh) {
        #pragma unroll
        for (int j = 0; j < 8; ++j) {
          const int r0  = 2 * j;
          const int k0r = (r0 & 3) + 8 * (r0 >> 2) + 4 * hi;
          const float p0 = (k0r     > ql) ? 0.f : __expf(sacc[r0]);
          const float p1 = (k0r + 1 > ql) ? 0.f : __expf(sacc[r0 + 1]);
          lsum += p0 + p1;
          u[j] = pack2t(p0, p1);
        }
      } else {
        #pragma unroll
        for (int j = 0; j < 8; ++j) {
          const float p0 = __expf(sacc[2 * j]);
          const float p1 = __expf(sacc[2 * j + 1]);
          lsum += p0 + p1;
          u[j] = pack2t(p0, p1);
        }
      }

      // P^T B-frags in-register: swap k-row pair-groups across lane halves.
      swap32p(u[0], u[2]); swap32p(u[1], u[3]);      // ks=0: k-rows 8hi+0..7
      swap32p(u[4], u[6]); swap32p(u[5], u[7]);      // ks=1
      const bf16x8 pf0 = __builtin_bit_cast(bf16x8, (u32x4){u[0], u[1], u[2], u[3]});
      const bf16x8 pf1 = __builtin_bit_cast(bf16x8, (u32x4){u[4], u[5], u[6], u[7]});

      // O^T += V^T P^T (A = V^T[d 32-rows x 16 k], per d-tile, per 16-k step)
      __builtin_amdgcn_s_setprio(1);
      #pragma unroll
      for (int dt = 0; dt < 2; ++dt) {
        f32x16& oa = dt ? oacc1 : oacc0;
        const int d = dt * 32 + ql;
        bf16x8 vf0 = *(const bf16x8*)&Vtd[cur * 2048 + d * 32 + 4 * ((4 * kh + hi) ^ (ql & 7))];
        oa = __builtin_amdgcn_mfma_f32_32x32x16_bf16(vf0, pf0, oa, 0, 0, 0);
        bf16x8 vf1 = *(const bf16x8*)&Vtd[cur * 2048 + d * 32 + 4 * ((4 * kh + 2 + hi) ^ (ql & 7))];
        oa = __builtin_amdgcn_mfma_f32_32x32x16_bf16(vf1, pf1, oa, 0, 0, 0);
      }
      __builtin_amdgcn_s_setprio(0);
    }

    if (havenext) writeV(cur ^ 1, va, vb);
    cur ^= 1;
  }

  // l: combine the two hi-halves (each covers half the wave's k-rows)
  lsum += __shfl_xor(lsum, 32);

  // ---- combine the two k-half waves' partials (O = O0 + O1, l = l0 + l1) ----
  __syncthreads();   // all K/V LDS use done before overlaying combine area
  if (kh == 1) {
    #pragma unroll
    for (int dt = 0; dt < 2; ++dt)
      #pragma unroll
      for (int rq = 0; rq < 4; ++rq) {
        const f32x16& oa = dt ? oacc1 : oacc0;
        *(f32x4*)&Ocmb[(qh * 8 + dt * 4 + rq) * 256 + lane * 4] =
            (f32x4){oa[4 * rq], oa[4 * rq + 1], oa[4 * rq + 2], oa[4 * rq + 3]};
      }
    if (hi == 0) Lcmb[qh * 32 + ql] = lsum;
  }
  __syncthreads();
  if (kh == 0) {
    const float inv = 1.f / (lsum + Lcmb[qh * 32 + ql]);
    u16* yp = y + (rb + qb + ql) * 1024 + hh * 64;
    #pragma unroll
    for (int dt = 0; dt < 2; ++dt)
      #pragma unroll
      for (int rq = 0; rq < 4; ++rq) {
        const f32x16& oa = dt ? oacc1 : oacc0;
        const f32x4 oc = *(const f32x4*)&Ocmb[(qh * 8 + dt * 4 + rq) * 256 + lane * 4];
        const float v0 = (oa[4 * rq]     + oc[0]) * inv;
        const float v1 = (oa[4 * rq + 1] + oc[1]) * inv;
        const float v2 = (oa[4 * rq + 2] + oc[2]) * inv;
        const float v3 = (oa[4 * rq + 3] + oc[3]) * inv;
        // d = dt*32 + 8*rq + 4*hi + {0..3}
        *(uint2*)(yp + dt * 32 + 8 * rq + 4 * hi) = make_uint2(pack2(v0, v1), pack2(v2, v3));
      }
  }
}

// ---------------------------------------------------------------------------
extern "C" void kernel_launch(void* const* d_in, const int* in_sizes, int n_in,
                              void* d_out, int out_size, void* d_ws, size_t ws_size,
                              hipStream_t stream)
{
  const float* x    = (const float*)d_in[0];   // [B*L, 1024] fp32
  const float* Wqkv = (const float*)d_in[1];   // [3072, 1024] fp32
  const float* Wo   = (const float*)d_in[2];   // [1024, 1024] fp32
  float* out = (float*)d_out;                  // [B*L, 1024] fp32

  u16* xb    = (u16*)d_ws;                      // [4096,1024]  8 MiB
  u16* Wqkvb = xb    + (size_t)4096 * 1024;     // [3072,1024]  6 MiB
  u16* Wob   = Wqkvb + (size_t)3072 * 1024;     // [1024,1024]  2 MiB
  u16* qkv   = Wob   + (size_t)1024 * 1024;     // [4096,3072] 24 MiB
  u16* y     = qkv   + (size_t)4096 * 3072;     // [4096,1024]  8 MiB

  cvt3_kernel<<<dim3(2048), dim3(256), 0, stream>>>(
      (const float4*)x,    (uint2*)xb,    4096 * 1024 / 4,
      (const float4*)Wqkv, (uint2*)Wqkvb, 3072 * 1024 / 4,
      (const float4*)Wo,   (uint2*)Wob,   1024 * 1024 / 4);

  // qkv = x @ Wqkv^T   (M=4096, N=3072, K=1024)  [R16: back to R12-best NT=128]
  gemm_bt_kernel<false, 128, false><<<dim3(3072 / 128, 4096 / 128), dim3(256), 0, stream>>>(
      xb, Wqkvb, qkv, 1024, 3072);
  // causal MHA -> y [4096, 1024] bf16  (R12 structure + longest-first remap)
  attn_mfma_kernel<<<dim3(B_ * H_, 32), dim3(256), 0, stream>>>(qkv, y);
  // out = y @ Wo^T     (M=4096, N=1024, K=1024), fp32 out
  gemm_bt_kernel<true, 64, true><<<dim3(1024 / 64, 4096 / 128), dim3(256), 0, stream>>>(
      y, Wob, out, 1024, 1024);
}

// Round 8
// 158.699 us; speedup vs baseline: 1.0479x; 1.0355x over previous
//
#include <hip/hip_runtime.h>

typedef unsigned short u16;
typedef unsigned int   u32;

typedef __attribute__((ext_vector_type(4)))  float  f32x4;
typedef __attribute__((ext_vector_type(16))) float  f32x16;
typedef __attribute__((ext_vector_type(4)))  u32    u32x4;
typedef __attribute__((ext_vector_type(8)))  __bf16 bf16x8;

#define B_  2
#define L_  2048
#define H_  16

// ---------- bf16 helpers ----------
__device__ static inline u16 f2bf(float f) {
  u32 u = __builtin_bit_cast(u32, f);
  u32 r = u + 0x7fffu + ((u >> 16) & 1u);
  return (u16)(r >> 16);
}
__device__ static inline u32 pack2(float a, float b) {   // RTNE pair pack
  return (u32)f2bf(a) | ((u32)f2bf(b) << 16);
}
// one-instruction truncating pair pack: dst = {hi16(b), hi16(a)} via v_perm_b32
__device__ static inline u32 pack2t(float a, float b) {
  return __builtin_amdgcn_perm(__builtin_bit_cast(u32, b),
                               __builtin_bit_cast(u32, a), 0x07060302u);
}

// permlane32_swap: a' = {a.lo32lanes, b.lo32lanes}, b' = {a.hi32lanes, b.hi32lanes}
__device__ static inline void swap32p(u32& a, u32& b) {
  auto r = __builtin_amdgcn_permlane32_swap(a, b, false, false);
  a = r[0]; b = r[1];
}

// async global->LDS, 16B/lane. LDS dest = wave-uniform base + lane*16.
__device__ static inline void gload_lds16(const u16* g, u16* lds) {
  __builtin_amdgcn_global_load_lds((__attribute__((address_space(1))) void*)(g),
                                   (__attribute__((address_space(3))) void*)(lds),
                                   16, 0, 0);
}

// ---------------------------------------------------------------------------
// fused fp32 -> bf16 pack for x, Wqkv, Wo (RTNE — GEMM inputs keep accuracy).
// softmax 1/sqrt(dk)=0.125 folded into W_q rows (power-of-2: bit-identical P).
// ---------------------------------------------------------------------------
__global__ __launch_bounds__(256) void cvt3_kernel(
    const float4* __restrict__ a, uint2* __restrict__ ao, int na,
    const float4* __restrict__ b, uint2* __restrict__ bo, int nb,
    const float4* __restrict__ c, uint2* __restrict__ co, int nc)
{
  const int step = gridDim.x * 256;
  constexpr int nq = 1024 * 1024 / 4;          // float4 count of the W_q rows
  for (int i = blockIdx.x * 256 + threadIdx.x; i < na; i += step) {
    float4 f = a[i];
    ao[i] = make_uint2(pack2(f.x, f.y), pack2(f.z, f.w));
  }
  for (int i = blockIdx.x * 256 + threadIdx.x; i < nb; i += step) {
    float4 f = b[i];
    const float s = (i < nq) ? 0.125f : 1.0f;
    bo[i] = make_uint2(pack2(f.x * s, f.y * s), pack2(f.z * s, f.w * s));
  }
  for (int i = blockIdx.x * 256 + threadIdx.x; i < nc; i += step) {
    float4 f = c[i];
    co[i] = make_uint2(pack2(f.x, f.y), pack2(f.z, f.w));
  }
}

// ---------------------------------------------------------------------------
// GEMM: C[M,N] = A[M,K] @ Bt[N,K]^T, bf16 in, fp32 MFMA accumulate.
// m97 structure + source-permuted XOR chunk swizzle (R6).
// R17: __launch_bounds__(256,4) caps VGPR at 128 (was 164, which silently
// limited occupancy to 3 waves/SIMD every round). Paired with NT=96 for
// GEMM1: grid 32x32 = 1024 blocks -> a true 4 blocks/CU (R15 ran this grid
// but the 164-VGPR cap kept it at 3 resident — paid the small-tile cost,
// got none of the TLP). JT=3 register budget: acc 48 + frags 28 + addr ~35
// = ~115 < 128, so the cap should be met without K-loop spills.
// GEMM2 keeps NT=64 + DBUF (JT=2, well under the cap).
// ---------------------------------------------------------------------------
template <bool OUT_F32, int NT, bool DBUF>
__global__ __launch_bounds__(256, 4) void gemm_bt_kernel(
    const u16* __restrict__ A, const u16* __restrict__ Bt, void* __restrict__ Cv,
    const int K, const int N)
{
  constexpr int NB = DBUF ? 2 : 1;
  constexpr int JT = NT / 32;                    // j-tiles per wave
  __shared__ __attribute__((aligned(16))) u16 Al[NB][128 * 64];
  __shared__ __attribute__((aligned(16))) u16 Bl[NB][NT * 64];

  const int tid  = threadIdx.x;
  const int w    = tid >> 6;
  const int lane = tid & 63;
  const int m0 = blockIdx.y * 128;
  const int n0 = blockIdx.x * NT;
  const int mo = (w >> 1) * 64;
  const int no = (w & 1) * (NT / 2);

  const int sr8  = lane >> 3;                    // staging row-in-group
  const int scol = (((lane & 7) ^ ((lane >> 3) & 7)) * 8);   // swizzled source chunk

  const f32x4 zero = {0.f, 0.f, 0.f, 0.f};
  f32x4 acc[4][JT];
  #pragma unroll
  for (int i = 0; i < 4; ++i)
    #pragma unroll
    for (int j = 0; j < JT; ++j) acc[i][j] = zero;

  const int frow = lane & 15;
  const int fg   = lane >> 4;

  auto stage = [&](int buf, int k0) {
    #pragma unroll
    for (int inst = 0; inst < 4; ++inst) {
      const int r = w * 32 + inst * 8 + sr8;
      gload_lds16(A + (size_t)(m0 + r) * K + k0 + scol, &Al[buf][(w * 32 + inst * 8) * 64]);
    }
    #pragma unroll
    for (int inst = 0; inst < NT / 32; ++inst) {
      const int r = w * (NT / 4) + inst * 8 + sr8;
      gload_lds16(Bt + (size_t)(n0 + r) * K + k0 + scol, &Bl[buf][(w * (NT / 4) + inst * 8) * 64]);
    }
  };

  if (DBUF) stage(0, 0);

  int cur = 0;
  for (int k0 = 0; k0 < K; k0 += 64) {
    __syncthreads();
    if (DBUF) {
      if (k0 + 64 < K) stage(cur ^ 1, k0 + 64);
    } else {
      stage(0, k0);
      __syncthreads();
    }
    #pragma unroll
    for (int ks = 0; ks < 2; ++ks) {
      const int fco = ((ks * 4 + fg) ^ (frow & 7)) * 8;      // swizzled read chunk
      bf16x8 af[4], bfr[JT];
      #pragma unroll
      for (int i = 0; i < 4; ++i)
        af[i] = *(const bf16x8*)&Al[cur][(mo + i * 16 + frow) * 64 + fco];
      #pragma unroll
      for (int j = 0; j < JT; ++j)
        bfr[j] = *(const bf16x8*)&Bl[cur][(no + j * 16 + frow) * 64 + fco];
      #pragma unroll
      for (int i = 0; i < 4; ++i)
        #pragma unroll
        for (int j = 0; j < JT; ++j)
          acc[i][j] = __builtin_amdgcn_mfma_f32_16x16x32_bf16(af[i], bfr[j], acc[i][j], 0, 0, 0);
    }
    if (DBUF) cur ^= 1;
  }

  const int crow0 = m0 + mo + (lane >> 4) * 4;
  const int ccol0 = n0 + no + (lane & 15);
  #pragma unroll
  for (int i = 0; i < 4; ++i)
    #pragma unroll
    for (int j = 0; j < JT; ++j)
      #pragma unroll
      for (int r = 0; r < 4; ++r) {
        const size_t idx = (size_t)(crow0 + i * 16 + r) * N + (ccol0 + j * 16);
        if (OUT_F32) ((float*)Cv)[idx] = acc[i][j][r];
        else         ((u16*)Cv)[idx]   = f2bf(acc[i][j][r]);
      }
}

// ---------------------------------------------------------------------------
// MFMA causal flash attention — exact R12 structure (best measured: 159.2).
// 32x32 MFMA, 256 thr, 4 waves (qh x kh), 4 blocks/CU (all 1024 blocks
// co-resident -> dispatch-order remaps are provably neutral, R16 lesson).
// P in-register via permlane32_swap, k-half combine via LDS overlay.
// ---------------------------------------------------------------------------
__global__ __launch_bounds__(256, 4) void attn_mfma_kernel(const u16* __restrict__ qkv,
                                                           u16* __restrict__ y)
{
  __shared__ __attribute__((aligned(16))) unsigned char smem[32768];

  const int tid  = threadIdx.x;
  const int w    = tid >> 6;                   // wave 0..3
  const int lane = tid & 63;
  const int ql   = lane & 31;                  // q-col (also d-row / k-row index)
  const int hi   = lane >> 5;
  const int qh   = w >> 1;                     // q-half of the 64-q tile
  const int kh   = w & 1;                      // k-half split
  const int bh   = blockIdx.x;                 // bh on x => XCD affinity
  const int bb   = bh >> 4;
  const int hh   = bh & 15;
  const size_t rb = (size_t)bb * L_;

  // load-balance remap: blocks at id, id+256, id+512, id+768 (same CU under
  // round-robin dispatch) get qt = {a, 31-a, 8+a, 23-a} -> 66 tiles total.
  const int a  = blockIdx.y & 7;
  const int cc = blockIdx.y >> 3;
  const int qt = (cc == 0) ? a : (cc == 1) ? (31 - a) : (cc == 2) ? (8 + a) : (23 - a);

  u16* Kt   = (u16*)(smem);                    // [buf*4096 + row*64 + col] bf16
  u32* Vtd  = (u32*)(smem + 16384);            // [buf*2048 + d*32 + kp] u32
  float* Ocmb = (float*)smem;                  // combine overlay [16][256] f32
  float* Lcmb = (float*)(smem + 16384);        // combine overlay [64] f32

  // V staging: thread handles key-pair column kkp, d-rows dc*8 .. dc*8+7
  const int kkp = lane & 31;
  const int dc  = 2 * w + (lane >> 5);         // 0..7

  // K staging (R6 swizzle): wave w stages rows w*16 .. w*16+15
  const int ksr = w * 16 + (lane >> 3);
  const int ksc = (((lane & 7) ^ ((lane >> 3) & 7)) * 8);

  const int q0 = qt * 64;
  const int qb = q0 + qh * 32;                 // wave's q-base; lane's q = qb+ql
  const int n  = qt + 1;                       // k-tiles for this tile

  // Q B-frags (32x32x16): qf[s] = Q[qb+ql][d = 16s + 8hi .. +7], W_q pre-scaled
  bf16x8 qf[4];
  #pragma unroll
  for (int s = 0; s < 4; ++s)
    qf[s] = *(const bf16x8*)(qkv + (rb + qb + ql) * 3072 + hh * 64 + s * 16 + 8 * hi);

  f32x16 oacc0 = {}, oacc1 = {};               // O^T d-tiles 0/1 (64 d x 32 q)
  float lsum = 0.f;

  auto stageK = [&](int buf, int kt) {
    #pragma unroll
    for (int inst = 0; inst < 2; ++inst)
      gload_lds16(qkv + (rb + kt + ksr + inst * 8) * 3072 + 1024 + hh * 64 + ksc,
                  &Kt[buf * 4096 + (w * 16 + inst * 8) * 64]);
  };
  auto loadV = [&](int kt, uint4& va, uint4& vb) {
    const u16* vp = qkv + (rb + kt + 2 * kkp) * 3072 + 2048 + hh * 64 + dc * 8;
    va = *(const uint4*)vp;
    vb = *(const uint4*)(vp + 3072);
  };
  auto writeV = [&](int buf, uint4 va, uint4 vb) {
    u16 a16[8], b16[8];
    *(uint4*)a16 = va; *(uint4*)b16 = vb;
    #pragma unroll
    for (int i = 0; i < 8; ++i)
      Vtd[buf * 2048 + (dc * 8 + i) * 32 + 4 * ((kkp >> 2) ^ i) + (kkp & 3)] =
          (u32)a16[i] | ((u32)b16[i] << 16);
  };

  // ---- prologue: stage tile 0 into buffer 0 ----
  {
    stageK(0, 0);
    uint4 va, vb;
    loadV(0, va, vb);
    writeV(0, va, vb);
  }

  int cur = 0;
  for (int it = 0; it < n; ++it) {
    __syncthreads();   // publishes K/V[cur]

    const int  kt       = it * 64;
    const bool havenext = (it + 1) < n;
    uint4 va, vb;
    if (havenext) {
      stageK(cur ^ 1, kt + 64);
      loadV(kt + 64, va, vb);
    }

    const bool diag = (kt == q0);
    if (!(diag && kh > qh)) {                  // (qh=0,kh=1) diag tile: all masked
      // S^T = K Q^T over this wave's k-half: 32q x 32k, chained over d (4x16)
      f32x16 sacc = {};
      __builtin_amdgcn_s_setprio(1);
      #pragma unroll
      for (int s = 0; s < 4; ++s) {
        bf16x8 kf = *(const bf16x8*)&Kt[cur * 4096 + (kh * 32 + ql) * 64 +
                                        (((2 * s + hi) ^ (ql & 7)) * 8)];
        sacc = __builtin_amdgcn_mfma_f32_32x32x16_bf16(kf, qf[s], sacc, 0, 0, 0);
      }
      __builtin_amdgcn_s_setprio(0);

      // p = exp(s); triangular mask only when kh==qh on the diag tile.
      // k-row(reg r) = (r&3) + 8*(r>>2) + 4*hi; pack pairs (rows 2j,2j+1).
      u32 u[8];
      if (diag && kh == qh) {
        #pragma unroll
        for (int j = 0; j < 8; ++j) {
          const int r0  = 2 * j;
          const int k0r = (r0 & 3) + 8 * (r0 >> 2) + 4 * hi;
          const float p0 = (k0r     > ql) ? 0.f : __expf(sacc[r0]);
          const float p1 = (k0r + 1 > ql) ? 0.f : __expf(sacc[r0 + 1]);
          lsum += p0 + p1;
          u[j] = pack2t(p0, p1);
        }
      } else {
        #pragma unroll
        for (int j = 0; j < 8; ++j) {
          const float p0 = __expf(sacc[2 * j]);
          const float p1 = __expf(sacc[2 * j + 1]);
          lsum += p0 + p1;
          u[j] = pack2t(p0, p1);
        }
      }

      // P^T B-frags in-register: swap k-row pair-groups across lane halves.
      swap32p(u[0], u[2]); swap32p(u[1], u[3]);      // ks=0: k-rows 8hi+0..7
      swap32p(u[4], u[6]); swap32p(u[5], u[7]);      // ks=1
      const bf16x8 pf0 = __builtin_bit_cast(bf16x8, (u32x4){u[0], u[1], u[2], u[3]});
      const bf16x8 pf1 = __builtin_bit_cast(bf16x8, (u32x4){u[4], u[5], u[6], u[7]});

      // O^T += V^T P^T (A = V^T[d 32-rows x 16 k], per d-tile, per 16-k step)
      __builtin_amdgcn_s_setprio(1);
      #pragma unroll
      for (int dt = 0; dt < 2; ++dt) {
        f32x16& oa = dt ? oacc1 : oacc0;
        const int d = dt * 32 + ql;
        bf16x8 vf0 = *(const bf16x8*)&Vtd[cur * 2048 + d * 32 + 4 * ((4 * kh + hi) ^ (ql & 7))];
        oa = __builtin_amdgcn_mfma_f32_32x32x16_bf16(vf0, pf0, oa, 0, 0, 0);
        bf16x8 vf1 = *(const bf16x8*)&Vtd[cur * 2048 + d * 32 + 4 * ((4 * kh + 2 + hi) ^ (ql & 7))];
        oa = __builtin_amdgcn_mfma_f32_32x32x16_bf16(vf1, pf1, oa, 0, 0, 0);
      }
      __builtin_amdgcn_s_setprio(0);
    }

    if (havenext) writeV(cur ^ 1, va, vb);
    cur ^= 1;
  }

  // l: combine the two hi-halves (each covers half the wave's k-rows)
  lsum += __shfl_xor(lsum, 32);

  // ---- combine the two k-half waves' partials (O = O0 + O1, l = l0 + l1) ----
  __syncthreads();   // all K/V LDS use done before overlaying combine area
  if (kh == 1) {
    #pragma unroll
    for (int dt = 0; dt < 2; ++dt)
      #pragma unroll
      for (int rq = 0; rq < 4; ++rq) {
        const f32x16& oa = dt ? oacc1 : oacc0;
        *(f32x4*)&Ocmb[(qh * 8 + dt * 4 + rq) * 256 + lane * 4] =
            (f32x4){oa[4 * rq], oa[4 * rq + 1], oa[4 * rq + 2], oa[4 * rq + 3]};
      }
    if (hi == 0) Lcmb[qh * 32 + ql] = lsum;
  }
  __syncthreads();
  if (kh == 0) {
    const float inv = 1.f / (lsum + Lcmb[qh * 32 + ql]);
    u16* yp = y + (rb + qb + ql) * 1024 + hh * 64;
    #pragma unroll
    for (int dt = 0; dt < 2; ++dt)
      #pragma unroll
      for (int rq = 0; rq < 4; ++rq) {
        const f32x16& oa = dt ? oacc1 : oacc0;
        const f32x4 oc = *(const f32x4*)&Ocmb[(qh * 8 + dt * 4 + rq) * 256 + lane * 4];
        const float v0 = (oa[4 * rq]     + oc[0]) * inv;
        const float v1 = (oa[4 * rq + 1] + oc[1]) * inv;
        const float v2 = (oa[4 * rq + 2] + oc[2]) * inv;
        const float v3 = (oa[4 * rq + 3] + oc[3]) * inv;
        // d = dt*32 + 8*rq + 4*hi + {0..3}
        *(uint2*)(yp + dt * 32 + 8 * rq + 4 * hi) = make_uint2(pack2(v0, v1), pack2(v2, v3));
      }
  }
}

// ---------------------------------------------------------------------------
extern "C" void kernel_launch(void* const* d_in, const int* in_sizes, int n_in,
                              void* d_out, int out_size, void* d_ws, size_t ws_size,
                              hipStream_t stream)
{
  const float* x    = (const float*)d_in[0];   // [B*L, 1024] fp32
  const float* Wqkv = (const float*)d_in[1];   // [3072, 1024] fp32
  const float* Wo   = (const float*)d_in[2];   // [1024, 1024] fp32
  float* out = (float*)d_out;                  // [B*L, 1024] fp32

  u16* xb    = (u16*)d_ws;                      // [4096,1024]  8 MiB
  u16* Wqkvb = xb    + (size_t)4096 * 1024;     // [3072,1024]  6 MiB
  u16* Wob   = Wqkvb + (size_t)3072 * 1024;     // [1024,1024]  2 MiB
  u16* qkv   = Wob   + (size_t)1024 * 1024;     // [4096,3072] 24 MiB
  u16* y     = qkv   + (size_t)4096 * 3072;     // [4096,1024]  8 MiB

  cvt3_kernel<<<dim3(2048), dim3(256), 0, stream>>>(
      (const float4*)x,    (uint2*)xb,    4096 * 1024 / 4,
      (const float4*)Wqkv, (uint2*)Wqkvb, 3072 * 1024 / 4,
      (const float4*)Wo,   (uint2*)Wob,   1024 * 1024 / 4);

  // qkv = x @ Wqkv^T   (M=4096, N=3072, K=1024)
  // R17: NT=96 grid 32x32 = 1024 blocks + VGPR<=128 (launch_bounds) ->
  // a true 4 blocks/CU (R15's grid with the occupancy it never got).
  gemm_bt_kernel<false, 96, false><<<dim3(3072 / 96, 4096 / 128), dim3(256), 0, stream>>>(
      xb, Wqkvb, qkv, 1024, 3072);
  // causal MHA -> y [4096, 1024] bf16  (exact R12 structure)
  attn_mfma_kernel<<<dim3(B_ * H_, 32), dim3(256), 0, stream>>>(qkv, y);
  // out = y @ Wo^T     (M=4096, N=1024, K=1024), fp32 out
  gemm_bt_kernel<true, 64, true><<<dim3(1024 / 64, 4096 / 128), dim3(256), 0, stream>>>(
      y, Wob, out, 1024, 1024);
}